// Round 1
// 557.704 us; speedup vs baseline: 1.1089x; 1.1089x over previous
//
#include <hip/hip_runtime.h>
#include <hip/hip_bf16.h>
#include <cstdint>

#define BATCH 128
#define SEQ   512
#define EMB   300
#define HID   100
#define G3    300
#define NCLS  20
#define NROWS (SEQ * BATCH)

#define M1_WORDS 614400   // 128*512*300 / 32
#define M2_WORDS 204800   // 512*128*100 / 32

typedef __attribute__((ext_vector_type(4))) float f32x4;
typedef __attribute__((ext_vector_type(8))) short s16x8;
typedef __fp16 h16x2 __attribute__((ext_vector_type(2)));   // matches cvt_pkrtz return

// ---------------- threefry2x32 (JAX-compatible, verified round 1) ----------------
__host__ __device__ __forceinline__ void threefry2x32(uint32_t k0, uint32_t k1,
                                                      uint32_t x0, uint32_t x1,
                                                      uint32_t* o0, uint32_t* o1) {
  uint32_t ks2 = k0 ^ k1 ^ 0x1BD11BDAu;
  x0 += k0; x1 += k1;
#define TFR(r) { x0 += x1; x1 = (x1 << (r)) | (x1 >> (32 - (r))); x1 ^= x0; }
  TFR(13) TFR(15) TFR(26) TFR(6)  x0 += k1;  x1 += ks2 + 1u;
  TFR(17) TFR(29) TFR(16) TFR(24) x0 += ks2; x1 += k0 + 2u;
  TFR(13) TFR(15) TFR(26) TFR(6)  x0 += k0;  x1 += k1 + 3u;
  TFR(17) TFR(29) TFR(16) TFR(24) x0 += k1;  x1 += ks2 + 4u;
  TFR(13) TFR(15) TFR(26) TFR(6)  x0 += ks2; x1 += k0 + 5u;
#undef TFR
  *o0 = x0; *o1 = x1;
}

__device__ __forceinline__ uint32_t rand_bits32(uint32_t ka, uint32_t kb, uint32_t flat) {
  uint32_t a, b;
  threefry2x32(ka, kb, 0u, flat, &a, &b);
  return a ^ b;
}

__device__ __forceinline__ short f2bf(float f) {   // RNE fp32->bf16
  union { float f; uint32_t u; } c; c.f = f;
  uint32_t u = c.u;
  return (short)((u + 0x7FFFu + ((u >> 16) & 1u)) >> 16);
}

// raw barrier: LDS-only drain, no vmcnt(0)
__device__ __forceinline__ void bar_lds() {
  __asm__ __volatile__("s_waitcnt lgkmcnt(0)" ::: "memory");
  __builtin_amdgcn_s_barrier();
  __asm__ __volatile__("" ::: "memory");
}

// lane i <- lane i^4 (BitMode: xor=4, and=0x1F)
__device__ __forceinline__ float swz_xor4(float x) {
  return __builtin_bit_cast(float,
      __builtin_amdgcn_ds_swizzle(__builtin_bit_cast(int, x), 0x101F));
}

// ---------------- K0: precompute bit-packed dropout masks [unchanged] ----------------
__global__ __launch_bounds__(256) void k_mask(uint32_t* __restrict__ M1w,
                                              uint32_t* __restrict__ M2w,
                                              uint32_t k1a, uint32_t k1b,
                                              uint32_t k2a, uint32_t k2b) {
  const int i = blockIdx.x * 256 + threadIdx.x;
  uint32_t ka, kb, base;
  uint32_t* dst;
  if (i < M1_WORDS) { ka = k1a; kb = k1b; base = (uint32_t)i * 32u; dst = M1w + i; }
  else { ka = k2a; kb = k2b; base = (uint32_t)(i - M1_WORDS) * 32u; dst = M2w + (i - M1_WORDS); }
  uint32_t w = 0u;
#pragma unroll
  for (int j = 0; j < 32; ++j) {
    uint32_t bits = rand_bits32(ka, kb, base + (uint32_t)j);
    w |= ((~bits) >> 31) << j;
  }
  *dst = w;
}

// ---------------- K0c: pre-convert w_ih -> bf16, zero-padded Wb[304][320] ----------
__global__ __launch_bounds__(256) void k_prepw(const float* __restrict__ w_ih,
                                               short* __restrict__ Wb) {
  int i8 = (blockIdx.x * 256 + threadIdx.x) * 8;
  if (i8 >= 304 * 320) return;
  short o[8];
#pragma unroll
  for (int j = 0; j < 8; ++j) {
    int pos = i8 + j;
    int n = pos / 320, k = pos - (pos / 320) * 320;
    float v = (n < 300 && k < 300) ? w_ih[(size_t)n * EMB + k] : 0.f;
    o[j] = f2bf(v);
  }
  *(s16x8*)(Wb + i8) = *(s16x8*)o;
}

// ---------------- K1 v7: MFMA GI GEMM, one block per s [unchanged] ----------------
__global__ __launch_bounds__(512) void k_gi7(const int* __restrict__ inputs,
                                             const float* __restrict__ emb,
                                             const short* __restrict__ Wb,
                                             const float* __restrict__ b_ih,
                                             const uint32_t* __restrict__ M1w,
                                             float* __restrict__ GI) {
  __shared__ short As[128 * 40];
  __shared__ short Bs[304 * 40];
  __shared__ int idxs[128];
  const int t = threadIdx.x;
  const int s = blockIdx.x;
  const int lane = t & 63, wave = t >> 6;
  const int wr = wave & 1;
  const int wc = wave >> 1;
  const int ml = lane & 15, quad = lane >> 4;
  const int arow = t >> 2;
  const int akq = t & 3;

  if (t < 128) idxs[t] = inputs[t * SEQ + s];
  __syncthreads();

  const int nfr = (wc < 3) ? 5 : 4;
  f32x4 acc[4][5];
#pragma unroll
  for (int i = 0; i < 4; ++i)
#pragma unroll
    for (int j = 0; j < 5; ++j) acc[i][j] = (f32x4){0.f, 0.f, 0.f, 0.f};

  const int myidx = idxs[arow];

  for (int c = 0; c < 10; ++c) {
    const int e0 = c * 32 + akq * 8;
    float xa[8];
#pragma unroll
    for (int j = 0; j < 8; ++j) xa[j] = 0.f;
    if (e0 + 7 < 300) {
#pragma unroll
      for (int q4 = 0; q4 < 2; ++q4) {
        float4 v = *(const float4*)(emb + (size_t)myidx * EMB + e0 + q4 * 4);
        xa[q4 * 4 + 0] = v.x; xa[q4 * 4 + 1] = v.y; xa[q4 * 4 + 2] = v.z; xa[q4 * 4 + 3] = v.w;
      }
    } else if (e0 < 300) {
#pragma unroll
      for (int j = 0; j < 8; ++j) {
        int e = e0 + j;
        if (e < 300) xa[j] = emb[(size_t)myidx * EMB + e];
      }
    }
    uint32_t mb = 0;
    if (e0 < 300) {
      uint32_t base = (uint32_t)((arow * SEQ + s) * EMB + e0);
      uint64_t mw = (uint64_t)M1w[base >> 5] | ((uint64_t)M1w[(base >> 5) + 1] << 32);
      mb = (uint32_t)(mw >> (base & 31));
    }
    short sa[8];
#pragma unroll
    for (int j = 0; j < 8; ++j)
      sa[j] = f2bf(((mb >> j) & 1u) ? xa[j] * 2.f : 0.f);
    s16x8 bv0, bv1, bv2;
    {
      int i0 = t;
      bv0 = *(const s16x8*)(Wb + (size_t)(i0 >> 2) * 320 + c * 32 + (i0 & 3) * 8);
      int i1 = t + 512;
      bv1 = *(const s16x8*)(Wb + (size_t)(i1 >> 2) * 320 + c * 32 + (i1 & 3) * 8);
      if (t < 192) {
        int i2 = t + 1024;
        bv2 = *(const s16x8*)(Wb + (size_t)(i2 >> 2) * 320 + c * 32 + (i2 & 3) * 8);
      }
    }
    if (c > 0) __syncthreads();
    *(s16x8*)&As[arow * 40 + akq * 8] = *(s16x8*)&sa[0];
    {
      int i0 = t;       *(s16x8*)&Bs[(i0 >> 2) * 40 + (i0 & 3) * 8] = bv0;
      int i1 = t + 512; *(s16x8*)&Bs[(i1 >> 2) * 40 + (i1 & 3) * 8] = bv1;
      if (t < 192) { int i2 = t + 1024; *(s16x8*)&Bs[(i2 >> 2) * 40 + (i2 & 3) * 8] = bv2; }
    }
    __syncthreads();
    s16x8 af[4];
#pragma unroll
    for (int mt = 0; mt < 4; ++mt)
      af[mt] = *(const s16x8*)&As[(wr * 64 + mt * 16 + ml) * 40 + quad * 8];
#pragma unroll
    for (int j = 0; j < 5; ++j) {
      if (j < nfr) {
        int nt = wc + 4 * j;
        s16x8 bf = *(const s16x8*)&Bs[(nt * 16 + ml) * 40 + quad * 8];
#pragma unroll
        for (int mt = 0; mt < 4; ++mt)
          acc[mt][j] = __builtin_amdgcn_mfma_f32_16x16x32_bf16(af[mt], bf, acc[mt][j], 0, 0, 0);
      }
    }
  }

#pragma unroll
  for (int j = 0; j < 5; ++j) {
    if (j < nfr) {
      int n = (wc + 4 * j) * 16 + ml;
      if (n < 300) {
        float bias = b_ih[n];
#pragma unroll
        for (int mt = 0; mt < 4; ++mt) {
#pragma unroll
          for (int i = 0; i < 4; ++i) {
            int brow = wr * 64 + mt * 16 + quad * 4 + i;
            GI[(size_t)(s * BATCH + brow) * G3 + n] = acc[mt][j][i] + bias;
          }
        }
      }
    }
  }
}

// ---------------- K2 v11: quad-split + DPP reduce, ONE barrier/step ----------------
// 128 blocks x 512 threads. lane t: unit u = t>>2 (u<100 active), k-slice ks = t&3
// (13/13/12/12 of the 50 h f16-pairs). Weights in regs (39 x h16x2 per lane).
// h: packed f16 pairs in LDS, DOUBLE-BUFFERED, slices padded to 16 dwords so each
// lane reads 3x ds_read_b128 + 1x ds_read_b32 (16B-aligned). Partial sums reduced
// across the quad with DPP quad_perm butterfly (no LDS, no extra barrier).
// ks==0 lane does gate math (hprev kept in-register), pairs hnew via ds_swizzle
// xor4, cvt_pkrtz-packs, writes one dword into the other h buffer. bar_lds once.
__global__ __launch_bounds__(512, 1) void k_rnn11(const float* __restrict__ GI,
                                                  const float* __restrict__ w_hh,
                                                  const float* __restrict__ b_hh,
                                                  const uint8_t* __restrict__ M2,
                                                  float* __restrict__ Hd) {
  __shared__ __align__(16) uint32_t hp_s[2][64];
  const int t = threadIdx.x, b = blockIdx.x;
  const int u = t >> 2, ks = t & 3;
  const bool act = (u < 100);
  const bool gate = act && (ks == 0);
  const int uc = act ? u : 99;
  const int kplo = (ks < 2) ? ks * 13 : 26 + (ks - 2) * 12;
  const int np = (ks < 2) ? 13 : 12;

  // per-lane weight fragments: rows u, u+100, u+200; pairs [kplo, kplo+np)
  const float* rowR = w_hh + (size_t)uc * HID;
  const float* rowZ = w_hh + (size_t)(uc + 100) * HID;
  const float* rowN = w_hh + (size_t)(uc + 200) * HID;
  const h16x2 z2 = (h16x2){(__fp16)0.f, (__fp16)0.f};
  h16x2 wR[13], wZ[13], wN[13];
#pragma unroll
  for (int j = 0; j < 13; ++j) {
    if (j < np) {
      int o = 2 * (kplo + j);
      wR[j] = __builtin_amdgcn_cvt_pkrtz(rowR[o], rowR[o + 1]);
      wZ[j] = __builtin_amdgcn_cvt_pkrtz(rowZ[o], rowZ[o + 1]);
      wN[j] = __builtin_amdgcn_cvt_pkrtz(rowN[o], rowN[o + 1]);
    } else { wR[j] = z2; wZ[j] = z2; wN[j] = z2; }  // padded 13th slot: zero weight
  }

  // biases folded into the ks==0 accumulator init; gi prefetch for s=0
  float bR0 = 0.f, bZ0 = 0.f, bN0 = 0.f;
  float gcR = 0.f, gcZ = 0.f, gcN = 0.f;
  uint8_t mc = 0;
  if (gate) {
    bR0 = b_hh[u]; bZ0 = b_hh[100 + u]; bN0 = b_hh[200 + u];
    const float* g0 = GI + (size_t)b * G3;
    gcR = g0[u]; gcZ = g0[100 + u]; gcN = g0[200 + u];
    mc = M2[(uint32_t)(b * HID + u) >> 3];
  }
  // writer: even-u gate lane packs pair p = u/2 into slice-padded slot
  const int p = u >> 1;
  const int sidx = (p < 13) ? 0 : (p < 26) ? 1 : (p < 38) ? 2 : 3;
  const int spos = p - ((sidx < 2) ? sidx * 13 : 26 + (sidx - 2) * 12);
  const int slot = sidx * 16 + spos;
  const bool writer = gate && !(u & 1);

  if (t < 128) ((uint32_t*)hp_s)[t] = 0u;   // zero both buffers incl. pad slots
  float hprev = 0.f;
  __syncthreads();

#define QPX(x, c) __builtin_bit_cast(float, __builtin_amdgcn_mov_dpp( \
    __builtin_bit_cast(int, (x)), (c), 0xF, 0xF, true))
#define DOT1(J, W) { h16x2 hh = __builtin_bit_cast(h16x2, (W)); \
    sR = __builtin_amdgcn_fdot2(wR[J], hh, sR, false); \
    sZ = __builtin_amdgcn_fdot2(wZ[J], hh, sZ, false); \
    sN = __builtin_amdgcn_fdot2(wN[J], hh, sN, false); }

#pragma unroll 2
  for (int s = 0; s < SEQ; ++s) {
    // prefetch next step's gi + mask byte (consumed next iteration)
    float gnR = 0.f, gnZ = 0.f, gnN = 0.f;
    uint8_t mn = 0;
    if (gate) {
      int sn = (s + 1 < SEQ) ? s + 1 : s;
      const float* gp = GI + (size_t)(sn * BATCH + b) * G3;
      gnR = gp[u]; gnZ = gp[100 + u]; gnN = gp[200 + u];
      mn = M2[(uint32_t)((sn * BATCH + b) * HID + u) >> 3];
    }
    if (act) {
      float sR = bR0, sZ = bZ0, sN = bN0;
      const uint32_t* hb = &hp_s[s & 1][0] + (ks << 4);
      uint4 h0 = *(const uint4*)hb;          // pairs 0-3 of my slice
      uint4 h1 = *(const uint4*)(hb + 4);    // pairs 4-7
      uint4 h2 = *(const uint4*)(hb + 8);    // pairs 8-11
      uint32_t h3 = hb[12];                  // pair 12 (zero-weighted for ks>=2)
      DOT1(0, h0.x)  DOT1(1, h0.y)  DOT1(2, h0.z)  DOT1(3, h0.w)
      DOT1(4, h1.x)  DOT1(5, h1.y)  DOT1(6, h1.z)  DOT1(7, h1.w)
      DOT1(8, h2.x)  DOT1(9, h2.y)  DOT1(10, h2.z) DOT1(11, h2.w)
      DOT1(12, h3)
      // quad butterfly: 0xB1 = quad_perm[1,0,3,2] (xor1), 0x4E = [2,3,0,1] (xor2)
      sR += QPX(sR, 0xB1); sZ += QPX(sZ, 0xB1); sN += QPX(sN, 0xB1);
      sR += QPX(sR, 0x4E); sZ += QPX(sZ, 0x4E); sN += QPX(sN, 0x4E);
      if (gate) {
        float r = 1.f / (1.f + __expf(-(gcR + sR)));
        float z = 1.f / (1.f + __expf(-(gcZ + sZ)));
        float xn = gcN + r * sN;
        float e2 = __expf(2.f * fabsf(xn));
        float n = copysignf(1.f - 2.f / (e2 + 1.f), xn);   // overflow-safe tanh
        float hnew = (1.f - z) * n + z * hprev;
        hprev = hnew;
        uint32_t fl = (uint32_t)((s * BATCH + b) * HID + u);
        float hd = ((mc >> (fl & 7)) & 1u) ? hnew * 2.f : 0.f;
        Hd[(size_t)(b * SEQ + s) * HID + u] = hd;   // store stays in flight
        float hoth = swz_xor4(hnew);                // partner lane (u^1) is active
        if (writer)
          hp_s[(s & 1) ^ 1][slot] =
              __builtin_bit_cast(uint32_t, __builtin_amdgcn_cvt_pkrtz(hnew, hoth));
      }
    }
    gcR = gnR; gcZ = gnZ; gcN = gnN; mc = mn;
    bar_lds();   // single barrier: write-buffer visible; read/write race impossible
  }
#undef DOT1
#undef QPX
}

// ---------------- K3: logits + log_softmax [unchanged] ----------------
__global__ __launch_bounds__(64) void k_out(const float* __restrict__ Hd,
                                            const float* __restrict__ w_lin,
                                            const float* __restrict__ b_lin,
                                            float* __restrict__ out) {
  __shared__ float Wl[NCLS * HID];
  __shared__ float bl[NCLS];
  const int t = threadIdx.x;
  for (int i = t; i < NCLS * HID; i += 64) Wl[i] = w_lin[i];
  if (t < NCLS) bl[t] = b_lin[t];
  __syncthreads();

  const int r0 = (blockIdx.x * 64 + t) * 4;
  float acc[4][NCLS];
#pragma unroll
  for (int r = 0; r < 4; ++r)
#pragma unroll
    for (int c = 0; c < NCLS; ++c) acc[r][c] = bl[c];

  for (int k = 0; k < HID; k += 4) {
    float4 h0 = *(const float4*)(Hd + (size_t)(r0 + 0) * HID + k);
    float4 h1 = *(const float4*)(Hd + (size_t)(r0 + 1) * HID + k);
    float4 h2 = *(const float4*)(Hd + (size_t)(r0 + 2) * HID + k);
    float4 h3 = *(const float4*)(Hd + (size_t)(r0 + 3) * HID + k);
#pragma unroll
    for (int c = 0; c < NCLS; ++c) {
      float4 w4 = *(const float4*)&Wl[c * HID + k];
      acc[0][c] += h0.x * w4.x + h0.y * w4.y + h0.z * w4.z + h0.w * w4.w;
      acc[1][c] += h1.x * w4.x + h1.y * w4.y + h1.z * w4.z + h1.w * w4.w;
      acc[2][c] += h2.x * w4.x + h2.y * w4.y + h2.z * w4.z + h2.w * w4.w;
      acc[3][c] += h3.x * w4.x + h3.y * w4.y + h3.z * w4.z + h3.w * w4.w;
    }
  }

  float lse[4];
#pragma unroll
  for (int r = 0; r < 4; ++r) {
    float mx = acc[r][0];
#pragma unroll
    for (int c = 1; c < NCLS; ++c) mx = fmaxf(mx, acc[r][c]);
    float se = 0.f;
#pragma unroll
    for (int c = 0; c < NCLS; ++c) se += __expf(acc[r][c] - mx);
    lse[r] = mx + __logf(se);
  }
  const int b = r0 >> 9, s0 = r0 & 511;
#pragma unroll
  for (int c = 0; c < NCLS; ++c) {
    float4 o = make_float4(acc[0][c] - lse[0], acc[1][c] - lse[1],
                           acc[2][c] - lse[2], acc[3][c] - lse[3]);
    *(float4*)(out + (size_t)(b * NCLS + c) * SEQ + s0) = o;
  }
}

// ---------------- host ----------------
extern "C" void kernel_launch(void* const* d_in, const int* in_sizes, int n_in,
                              void* d_out, int out_size, void* d_ws, size_t ws_size,
                              hipStream_t stream) {
  const int*   inputs = (const int*)d_in[0];
  const float* emb    = (const float*)d_in[1];
  const float* w_ih   = (const float*)d_in[2];
  const float* w_hh   = (const float*)d_in[3];
  const float* b_ih   = (const float*)d_in[4];
  const float* b_hh   = (const float*)d_in[5];
  const float* w_lin  = (const float*)d_in[6];
  const float* b_lin  = (const float*)d_in[7];
  float* out = (float*)d_out;

  float* GI = (float*)d_ws;                           // 78.6 MB
  float* Hd = GI + (size_t)NROWS * G3;                // 26.2 MB
  uint8_t* M1 = (uint8_t*)(Hd + (size_t)NROWS * HID); // 2.46 MB
  uint8_t* M2 = M1 + (size_t)M1_WORDS * 4;            // 0.82 MB
  short* Wb = (short*)(M2 + (size_t)M2_WORDS * 4);    // 190 KB

  uint32_t dk1a, dk1b, dk2a, dk2b;
  threefry2x32(0u, 42u, 0u, 0u, &dk1a, &dk1b);
  threefry2x32(0u, 42u, 0u, 1u, &dk2a, &dk2b);

  k_mask<<<(M1_WORDS + M2_WORDS) / 256, 256, 0, stream>>>(
      (uint32_t*)M1, (uint32_t*)M2, dk1a, dk1b, dk2a, dk2b);
  k_prepw<<<(304 * 320 / 8 + 255) / 256, 256, 0, stream>>>(w_ih, Wb);
  k_gi7<<<512, 512, 0, stream>>>(inputs, emb, Wb, b_ih, (const uint32_t*)M1, GI);
  k_rnn11<<<BATCH, 512, 0, stream>>>(GI, w_hh, b_hh, M2, Hd);
  k_out<<<256, 64, 0, stream>>>(Hd, w_lin, b_lin, out);
}